// Round 1
// baseline (285.041 us; speedup 1.0000x reference)
//
#include <hip/hip_runtime.h>
#include <math.h>

#define PATCH 96
#define STRIDE 48
#define NH 21
#define NW 21
#define NP (NH * NW)          // 441 patches per (b,c)
#define BATCH 8
#define CHAN 4
#define NBC (BATCH * CHAN)    // 32
#define TOTAL_PATCHES (NBC * NP)  // 14112
#define IMG_H 1056
#define IMG_W 1056
#define NPIX (PATCH * PATCH)      // 9216
#define NGRAD (PATCH * (PATCH-1)) // 9120

// ---------------------------------------------------------------------------
// Kernel 1: one block per patch. Stage patch in LDS via float4, compute
// sum, sumsq, sum(gx^2), sum(gy^2); write (mu, var, grad_mag) to ws.
// ---------------------------------------------------------------------------
__global__ __launch_bounds__(256) void patch_stats_kernel(
    const float* __restrict__ x, float* __restrict__ pf) {
  __shared__ float tile[PATCH * PATCH];   // 36 KB
  __shared__ float red[4][4];

  const int blk = blockIdx.x;
  const int bc = blk / NP;
  const int p  = blk - bc * NP;
  const int ph = p / NW;
  const int pw = p - ph * NW;
  const float* base = x + (size_t)bc * (IMG_H * IMG_W)
                        + (size_t)(ph * STRIDE) * IMG_W
                        + (size_t)(pw * STRIDE);
  const int t = threadIdx.x;

  // Stage: 96 rows * 24 float4 = 2304 quads; 9 per thread. All aligned 16B.
#pragma unroll
  for (int k = 0; k < 9; ++k) {
    int q  = t + k * 256;
    int i  = q / 24;
    int c4 = q - i * 24;
    float4 v = *(const float4*)(base + (size_t)i * IMG_W + c4 * 4);
    *(float4*)(tile + i * PATCH + c4 * 4) = v;
  }
  __syncthreads();

  float s1 = 0.f, s2 = 0.f, sgx = 0.f, sgy = 0.f;
#pragma unroll
  for (int k = 0; k < 9; ++k) {
    int q  = t + k * 256;
    int i  = q / 24;
    int c4 = q - i * 24;
    const float4 A = *(const float4*)(tile + i * PATCH + c4 * 4);
    s1 += A.x + A.y + A.z + A.w;
    s2 += A.x * A.x + A.y * A.y + A.z * A.z + A.w * A.w;
    float d1 = A.y - A.x, d2 = A.z - A.y, d3 = A.w - A.z;
    float g = d1 * d1 + d2 * d2 + d3 * d3;
    if (c4 < 23) {
      float r = tile[i * PATCH + c4 * 4 + 4];
      float d4 = r - A.w;
      g += d4 * d4;
    }
    sgx += g;
    if (i < PATCH - 1) {
      const float4 D = *(const float4*)(tile + (i + 1) * PATCH + c4 * 4);
      float e0 = D.x - A.x, e1 = D.y - A.y, e2 = D.z - A.z, e3 = D.w - A.w;
      sgy += e0 * e0 + e1 * e1 + e2 * e2 + e3 * e3;
    }
  }

  // Wave (64-lane) shuffle reduce, then cross-wave via LDS.
#pragma unroll
  for (int off = 32; off > 0; off >>= 1) {
    s1  += __shfl_xor(s1, off);
    s2  += __shfl_xor(s2, off);
    sgx += __shfl_xor(sgx, off);
    sgy += __shfl_xor(sgy, off);
  }
  const int wave = t >> 6;
  const int lane = t & 63;
  if (lane == 0) {
    red[wave][0] = s1; red[wave][1] = s2; red[wave][2] = sgx; red[wave][3] = sgy;
  }
  __syncthreads();
  if (t == 0) {
    float S1 = 0, S2 = 0, Sgx = 0, Sgy = 0;
#pragma unroll
    for (int w = 0; w < 4; ++w) {
      S1 += red[w][0]; S2 += red[w][1]; Sgx += red[w][2]; Sgy += red[w][3];
    }
    const float n = (float)NPIX;
    float mu  = S1 / n;
    float var = (S2 - S1 * S1 / n) / (n - 1.f);   // ddof=1
    float gmag = sqrtf(Sgx / (float)NGRAD + Sgy / (float)NGRAD);
    pf[blk * 3 + 0] = mu;
    pf[blk * 3 + 1] = var;
    pf[blk * 3 + 2] = gmag;
  }
}

// ---------------------------------------------------------------------------
// Kernel 2: single block. Reduce patches -> feats(8,12); invert cov[:12,:12]
// (double Gauss-Jordan w/ partial pivot); Mahalanobis per batch; mean.
// ---------------------------------------------------------------------------
__global__ __launch_bounds__(512) void finalize_kernel(
    const float* __restrict__ pf, const float* __restrict__ mu0_full,
    const float* __restrict__ cov_full, float* __restrict__ out) {
  __shared__ float feats[NBC * 3];   // [b][j], j in [0,12): 0-3 mu, 4-7 var, 8-11 gmag
  __shared__ double M[12][24];
  __shared__ float dist[BATCH];

  const int t = threadIdx.x;
  const int wave = t >> 6;
  const int lane = t & 63;

  // 96 features, 8 waves -> 12 features per wave.
  for (int fi = wave; fi < 96; fi += 8) {
    int b = fi / 12, j = fi - b * 12;
    int kind = j >> 2, c = j & 3;
    const float* src = pf + ((size_t)((b * CHAN + c) * NP)) * 3 + kind;
    float s = 0.f;
    for (int q = lane; q < NP; q += 64) s += src[q * 3];
#pragma unroll
    for (int off = 32; off > 0; off >>= 1) s += __shfl_xor(s, off);
    if (lane == 0) feats[fi] = s / (float)NP;
  }
  __syncthreads();

  // Invert 12x12 on thread 0 (double, partial pivoting). Tiny cost.
  if (t == 0) {
    for (int r = 0; r < 12; ++r)
      for (int c = 0; c < 12; ++c) {
        M[r][c] = (double)cov_full[r * 36 + c];
        M[r][12 + c] = (r == c) ? 1.0 : 0.0;
      }
    for (int k = 0; k < 12; ++k) {
      int pr = k;
      double best = fabs(M[k][k]);
      for (int r = k + 1; r < 12; ++r) {
        double a = fabs(M[r][k]);
        if (a > best) { best = a; pr = r; }
      }
      if (pr != k) {
        for (int c = 0; c < 24; ++c) {
          double tmp = M[k][c]; M[k][c] = M[pr][c]; M[pr][c] = tmp;
        }
      }
      double piv = M[k][k];
      for (int c = 0; c < 24; ++c) M[k][c] /= piv;
      for (int r = 0; r < 12; ++r) {
        if (r == k) continue;
        double f = M[r][k];
        if (f != 0.0)
          for (int c = 0; c < 24; ++c) M[r][c] -= f * M[k][c];
      }
    }
  }
  __syncthreads();

  if (t < BATCH) {
    int b = t;
    double acc = 0.0;
    for (int i = 0; i < 12; ++i) {
      double di = (double)feats[b * 12 + i] - (double)mu0_full[i];
      for (int j = 0; j < 12; ++j) {
        double dj = (double)feats[b * 12 + j] - (double)mu0_full[j];
        acc += di * M[i][12 + j] * dj;
      }
    }
    dist[b] = (float)sqrt(acc);
  }
  __syncthreads();
  if (t == 0) {
    float m = 0.f;
#pragma unroll
    for (int b = 0; b < BATCH; ++b) m += dist[b];
    out[0] = m / (float)BATCH;
  }
}

extern "C" void kernel_launch(void* const* d_in, const int* in_sizes, int n_in,
                              void* d_out, int out_size, void* d_ws, size_t ws_size,
                              hipStream_t stream) {
  const float* x   = (const float*)d_in[0];
  const float* mu0 = (const float*)d_in[1];
  const float* cov = (const float*)d_in[2];
  float* out = (float*)d_out;
  float* pf  = (float*)d_ws;   // TOTAL_PATCHES * 3 floats = 169 KB

  patch_stats_kernel<<<TOTAL_PATCHES, 256, 0, stream>>>(x, pf);
  finalize_kernel<<<1, 512, 0, stream>>>(pf, mu0, cov, out);
}

// Round 2
// 239.494 us; speedup vs baseline: 1.1902x; 1.1902x over previous
//
#include <hip/hip_runtime.h>
#include <math.h>

#define PATCH 96
#define STRIDE 48
#define NH 21
#define NW 21
#define NP (NH * NW)              // 441 patches per (b,c)
#define BATCH 8
#define CHAN 4
#define NBC (BATCH * CHAN)        // 32
#define IMG_H 1056
#define IMG_W 1056
#define NBAND 22                  // 48-row bands
#define NCHUNK 22                 // 48-col chunks
#define NSTAT 6                   // s1, s2, gxi, gxb, gyi, gyb
#define NPIX 9216.0f
#define NGRAD 9120.0f

// ---------------------------------------------------------------------------
// Phase 1: one block per (bc, band). Read 48(+1) rows once, coalesced float4.
// Thread t owns 4 contiguous cols [4t, 4t+4); 264 active threads cover 1056.
// Accumulate per-chunk partials: s1=sum x, s2=sum x^2, gxi=gx^2 internal to
// window when chunk is left/right member, gxb=gx^2 of the chunk-boundary diff,
// gyi=gy^2 of the 47 row-pairs inside the band, gyb=gy^2 of the band-boundary
// row pair. Reduce via LDS atomics (12 threads/chunk), write 132 floats.
// ---------------------------------------------------------------------------
__global__ __launch_bounds__(320) void band_stats_kernel(
    const float* __restrict__ x, float* __restrict__ pf) {
  __shared__ float acc[NCHUNK * NSTAT];   // 528 B

  const int t = threadIdx.x;              // 0..319
  const int bc = blockIdx.x / NBAND;
  const int band = blockIdx.x - bc * NBAND;
  const bool active = t < 264;
  const int tc = active ? t : 263;        // clamp inactive lanes to safe addr
  const int lane = t & 63;

  const float* rowbase = x + (size_t)bc * (IMG_H * IMG_W)
                           + (size_t)(band * STRIDE) * IMG_W
                           + (size_t)(4 * tc);
  const int rmax = (band == NBAND - 1) ? 47 : 48;  // last band: no boundary row

  float s1 = 0.f, s2 = 0.f, gxi = 0.f, gxb = 0.f, gyi = 0.f, gyb = 0.f;
  float4 prev = make_float4(0.f, 0.f, 0.f, 0.f);
  const bool bnd_is_gxb = ((t % 12) == 11);  // last quad of its chunk

  for (int r = 0; r <= rmax; ++r) {
    const float4 A = *(const float4*)(rowbase + (size_t)r * IMG_W);
    if (r < 48) {
      s1 += A.x + A.y + A.z + A.w;
      s2 += A.x * A.x + A.y * A.y + A.z * A.z + A.w * A.w;
      // next column value: lane+1's A.x, except wave boundary (scalar reload)
      float nxt = __shfl_down(A.x, 1);
      if (lane == 63 && t < 263) nxt = rowbase[(size_t)r * IMG_W + 4];
      float d1 = A.y - A.x, d2 = A.z - A.y, d3 = A.w - A.z, d4 = nxt - A.w;
      gxi += d1 * d1 + d2 * d2 + d3 * d3;
      float bd = d4 * d4;                 // t==263: garbage -> gxb of chunk 21 (unused)
      if (bnd_is_gxb) gxb += bd; else gxi += bd;
    }
    if (r > 0) {
      float e0 = A.x - prev.x, e1 = A.y - prev.y,
            e2 = A.z - prev.z, e3 = A.w - prev.w;
      float g = e0 * e0 + e1 * e1 + e2 * e2 + e3 * e3;
      if (r < 48) gyi += g; else gyb += g;
    }
    prev = A;
  }

  for (int i = t; i < NCHUNK * NSTAT; i += 320) acc[i] = 0.f;
  __syncthreads();
  if (active) {
    const int chunk = t / 12;
    atomicAdd(&acc[chunk * NSTAT + 0], s1);
    atomicAdd(&acc[chunk * NSTAT + 1], s2);
    atomicAdd(&acc[chunk * NSTAT + 2], gxi);
    atomicAdd(&acc[chunk * NSTAT + 3], gxb);
    atomicAdd(&acc[chunk * NSTAT + 4], gyi);
    atomicAdd(&acc[chunk * NSTAT + 5], gyb);
  }
  __syncthreads();
  float* dst = pf + (size_t)(bc * NBAND + band) * (NCHUNK * NSTAT);
  for (int i = t; i < NCHUNK * NSTAT; i += 320) dst[i] = acc[i];
}

// ---------------------------------------------------------------------------
// Phase 2: one block per bc. Stage the bc's 22x22x6 slab in LDS; thread p<441
// combines its 2x2 cells into (mu, var, gmag); block-reduce to per-bc means.
// ---------------------------------------------------------------------------
__global__ __launch_bounds__(512) void patch_feats_kernel(
    const float* __restrict__ pf, float* __restrict__ featsG) {
  __shared__ float S[NBAND * NCHUNK * NSTAT];   // 11.6 KB
  __shared__ float wsum[8][3];

  const int bc = blockIdx.x;
  const int t = threadIdx.x;
  const float* src = pf + (size_t)bc * (NBAND * NCHUNK * NSTAT);
  for (int i = t; i < NBAND * NCHUNK * NSTAT; i += 512) S[i] = src[i];
  __syncthreads();

  float fmu = 0.f, fvar = 0.f, fg = 0.f;
  if (t < NP) {
    const int ph = t / NW, pw = t - ph * NW;
#define AT(b, c, s) S[((b) * NCHUNK + (c)) * NSTAT + (s)]
    float S1 = AT(ph, pw, 0) + AT(ph, pw + 1, 0) + AT(ph + 1, pw, 0) + AT(ph + 1, pw + 1, 0);
    float S2 = AT(ph, pw, 1) + AT(ph, pw + 1, 1) + AT(ph + 1, pw, 1) + AT(ph + 1, pw + 1, 1);
    float Gx = AT(ph, pw, 2) + AT(ph, pw, 3) + AT(ph, pw + 1, 2)
             + AT(ph + 1, pw, 2) + AT(ph + 1, pw, 3) + AT(ph + 1, pw + 1, 2);
    float Gy = AT(ph, pw, 4) + AT(ph, pw, 5) + AT(ph + 1, pw, 4)
             + AT(ph, pw + 1, 4) + AT(ph, pw + 1, 5) + AT(ph + 1, pw + 1, 4);
#undef AT
    fmu = S1 / NPIX;
    fvar = (S2 - S1 * S1 / NPIX) / (NPIX - 1.f);
    fg = sqrtf((Gx + Gy) / NGRAD);
  }
#pragma unroll
  for (int off = 32; off > 0; off >>= 1) {
    fmu += __shfl_xor(fmu, off);
    fvar += __shfl_xor(fvar, off);
    fg += __shfl_xor(fg, off);
  }
  const int wave = t >> 6;
  if ((t & 63) == 0) { wsum[wave][0] = fmu; wsum[wave][1] = fvar; wsum[wave][2] = fg; }
  __syncthreads();
  if (t == 0) {
    float m = 0.f, v = 0.f, g = 0.f;
#pragma unroll
    for (int w = 0; w < 8; ++w) { m += wsum[w][0]; v += wsum[w][1]; g += wsum[w][2]; }
    const int b = bc / CHAN, c = bc - b * CHAN;
    featsG[b * 12 + 0 + c] = m / (float)NP;
    featsG[b * 12 + 4 + c] = v / (float)NP;
    featsG[b * 12 + 8 + c] = g / (float)NP;
  }
}

// ---------------------------------------------------------------------------
// Finalize: single block. Parallel Gauss-Jordan (12x12, double, partial
// pivoting; 288 threads = one augmented cell each), then Mahalanobis + mean.
// ---------------------------------------------------------------------------
__global__ __launch_bounds__(320) void finalize_kernel(
    const float* __restrict__ featsG, const float* __restrict__ mu0_full,
    const float* __restrict__ cov_full, float* __restrict__ out) {
  __shared__ double M[12][24];
  __shared__ float feats_s[96];
  __shared__ float dist[BATCH];
  __shared__ int pr_s;

  const int t = threadIdx.x;
  if (t < 96) feats_s[t] = featsG[t];
  if (t < 288) {
    const int r = t / 24, c = t - r * 24;
    M[r][c] = (c < 12) ? (double)cov_full[r * 36 + c] : ((c - 12 == r) ? 1.0 : 0.0);
  }
  __syncthreads();

  for (int k = 0; k < 12; ++k) {
    if (t == 0) {
      int pr = k; double best = fabs(M[k][k]);
      for (int r = k + 1; r < 12; ++r) {
        double a = fabs(M[r][k]);
        if (a > best) { best = a; pr = r; }
      }
      pr_s = pr;
    }
    __syncthreads();
    const int pr = pr_s;
    if (pr != k && t < 24) { double tmp = M[k][t]; M[k][t] = M[pr][t]; M[pr][t] = tmp; }
    __syncthreads();
    const double piv = M[k][k];
    __syncthreads();
    if (t < 24) M[k][t] = M[k][t] / piv;
    __syncthreads();
    double f = 0.0, mkc = 0.0;
    const int r = t / 24, c = t - r * 24;
    if (t < 288) { f = M[r][k]; mkc = M[k][c]; }
    __syncthreads();
    if (t < 288 && r != k) M[r][c] -= f * mkc;
    __syncthreads();
  }

  if (t < BATCH) {
    double acc = 0.0;
    for (int i = 0; i < 12; ++i) {
      double di = (double)feats_s[t * 12 + i] - (double)mu0_full[i];
      for (int j = 0; j < 12; ++j) {
        double dj = (double)feats_s[t * 12 + j] - (double)mu0_full[j];
        acc += di * M[i][12 + j] * dj;
      }
    }
    dist[t] = (float)sqrt(acc);
  }
  __syncthreads();
  if (t == 0) {
    float m = 0.f;
#pragma unroll
    for (int b = 0; b < BATCH; ++b) m += dist[b];
    out[0] = m / (float)BATCH;
  }
}

extern "C" void kernel_launch(void* const* d_in, const int* in_sizes, int n_in,
                              void* d_out, int out_size, void* d_ws, size_t ws_size,
                              hipStream_t stream) {
  const float* x   = (const float*)d_in[0];
  const float* mu0 = (const float*)d_in[1];
  const float* cov = (const float*)d_in[2];
  float* out = (float*)d_out;
  float* pf     = (float*)d_ws;                                   // 32*22*132 floats = 371.7 KB
  float* featsG = pf + (size_t)NBC * NBAND * NCHUNK * NSTAT;      // 96 floats

  band_stats_kernel<<<NBC * NBAND, 320, 0, stream>>>(x, pf);
  patch_feats_kernel<<<NBC, 512, 0, stream>>>(pf, featsG);
  finalize_kernel<<<1, 320, 0, stream>>>(featsG, mu0, cov, out);
}

// Round 3
// 228.413 us; speedup vs baseline: 1.2479x; 1.0485x over previous
//
#include <hip/hip_runtime.h>
#include <math.h>

#define PATCH 96
#define STRIDE 48
#define NH 21
#define NW 21
#define NP (NH * NW)              // 441 patches per (b,c)
#define BATCH 8
#define CHAN 4
#define NBC (BATCH * CHAN)        // 32
#define IMG_H 1056
#define IMG_W 1056
#define NBAND 22                  // 48-row bands
#define NCHUNK 22                 // 48-col chunks
#define NSTAT 6                   // s1, s2, gxi, gxb, gyi, gyb
#define NPIX 9216.0f
#define NGRAD 9120.0f

// ---------------------------------------------------------------------------
// Phase 1: one block per (bc, band); 576 threads = two 288-thread teams, each
// handling 24 rows of the 48-row band (plus its trailing gy row). Thread owns
// 4 contiguous cols via float4 + one overlapping scalar load for the gx
// neighbor (L1 hit; no shuffle, no divergence). Per-chunk partials merged via
// LDS atomics, 132 floats written per block.
//   gxi/gxb: horizontal diffs, chunk-internal / chunk-boundary
//   gyi/gyb: vertical diffs, band-internal pairs / band-boundary pair (47,48)
// ---------------------------------------------------------------------------
__global__ __launch_bounds__(576) void band_stats_kernel(
    const float* __restrict__ x, float* __restrict__ pf) {
  __shared__ float acc[NCHUNK * NSTAT];   // 528 B

  const int t = threadIdx.x;              // 0..575
  const int bc = blockIdx.x / NBAND;
  const int band = blockIdx.x - bc * NBAND;
  const int team = (t >= 288) ? 1 : 0;
  const int tt = t - 288 * team;          // 0..287
  const bool active = tt < 264;
  const int tc = active ? tt : 263;       // clamp idle lanes to a safe column
  // neighbor offset: +4 except at image edge (clamped -> d4==0, lands in the
  // never-read gxb of chunk 21)
  const int noff = (tc == 263) ? 3 : 4;
  const int r0 = team * 24;

  const float* rowbase = x + (size_t)bc * (IMG_H * IMG_W)
                           + (size_t)(band * STRIDE + r0) * IMG_W
                           + (size_t)(4 * tc);

  float s1 = 0.f, s2 = 0.f, gxi = 0.f, gxb = 0.f, gyi = 0.f, gyb = 0.f;
  const bool bnd_is_gxb = ((tc % 12) == 11);   // last quad of its chunk

#define SUMS_GX(A, nxt)                                                  \
  do {                                                                   \
    s1 += (A).x + (A).y + (A).z + (A).w;                                 \
    s2 += (A).x * (A).x + (A).y * (A).y + (A).z * (A).z + (A).w * (A).w; \
    float d1 = (A).y - (A).x, d2 = (A).z - (A).y, d3 = (A).w - (A).z;    \
    float d4 = (nxt) - (A).w;                                            \
    gxi += d1 * d1 + d2 * d2 + d3 * d3;                                  \
    float bd = d4 * d4;                                                  \
    if (bnd_is_gxb) gxb += bd; else gxi += bd;                           \
  } while (0)

  float4 prev;
  {  // first row of team (sums/gx only)
    const float4 A = *(const float4*)rowbase;
    const float nxt = rowbase[noff];
    SUMS_GX(A, nxt);
    prev = A;
  }
#pragma unroll 4
  for (int r = 1; r < 24; ++r) {
    const float4 A = *(const float4*)(rowbase + (size_t)r * IMG_W);
    const float nxt = rowbase[(size_t)r * IMG_W + noff];
    SUMS_GX(A, nxt);
    const float e0 = A.x - prev.x, e1 = A.y - prev.y,
                e2 = A.z - prev.z, e3 = A.w - prev.w;
    gyi += e0 * e0 + e1 * e1 + e2 * e2 + e3 * e3;
    prev = A;
  }
  // trailing gy row: team0 -> pair (23,24) internal; team1 -> pair (47,48)
  // boundary (absent for the last band)
  if (team == 0 || band != NBAND - 1) {
    const float4 A = *(const float4*)(rowbase + (size_t)24 * IMG_W);
    const float e0 = A.x - prev.x, e1 = A.y - prev.y,
                e2 = A.z - prev.z, e3 = A.w - prev.w;
    const float g = e0 * e0 + e1 * e1 + e2 * e2 + e3 * e3;
    if (team == 0) gyi += g; else gyb += g;
  }
#undef SUMS_GX

  for (int i = t; i < NCHUNK * NSTAT; i += 576) acc[i] = 0.f;
  __syncthreads();
  if (active) {
    const int chunk = tc / 12;
    atomicAdd(&acc[chunk * NSTAT + 0], s1);
    atomicAdd(&acc[chunk * NSTAT + 1], s2);
    atomicAdd(&acc[chunk * NSTAT + 2], gxi);
    atomicAdd(&acc[chunk * NSTAT + 3], gxb);
    atomicAdd(&acc[chunk * NSTAT + 4], gyi);
    atomicAdd(&acc[chunk * NSTAT + 5], gyb);
  }
  __syncthreads();
  float* dst = pf + (size_t)(bc * NBAND + band) * (NCHUNK * NSTAT);
  for (int i = t; i < NCHUNK * NSTAT; i += 576) dst[i] = acc[i];
}

// ---------------------------------------------------------------------------
// Phase 2: one block per bc. Stage the bc's 22x22x6 slab in LDS; thread p<441
// combines its 2x2 cells into (mu, var, gmag); block-reduce to per-bc means.
// ---------------------------------------------------------------------------
__global__ __launch_bounds__(512) void patch_feats_kernel(
    const float* __restrict__ pf, float* __restrict__ featsG) {
  __shared__ float S[NBAND * NCHUNK * NSTAT];   // 11.6 KB
  __shared__ float wsum[8][3];

  const int bc = blockIdx.x;
  const int t = threadIdx.x;
  const float* src = pf + (size_t)bc * (NBAND * NCHUNK * NSTAT);
  for (int i = t; i < NBAND * NCHUNK * NSTAT; i += 512) S[i] = src[i];
  __syncthreads();

  float fmu = 0.f, fvar = 0.f, fg = 0.f;
  if (t < NP) {
    const int ph = t / NW, pw = t - ph * NW;
#define AT(b, c, s) S[((b) * NCHUNK + (c)) * NSTAT + (s)]
    float S1 = AT(ph, pw, 0) + AT(ph, pw + 1, 0) + AT(ph + 1, pw, 0) + AT(ph + 1, pw + 1, 0);
    float S2 = AT(ph, pw, 1) + AT(ph, pw + 1, 1) + AT(ph + 1, pw, 1) + AT(ph + 1, pw + 1, 1);
    float Gx = AT(ph, pw, 2) + AT(ph, pw, 3) + AT(ph, pw + 1, 2)
             + AT(ph + 1, pw, 2) + AT(ph + 1, pw, 3) + AT(ph + 1, pw + 1, 2);
    float Gy = AT(ph, pw, 4) + AT(ph, pw, 5) + AT(ph + 1, pw, 4)
             + AT(ph, pw + 1, 4) + AT(ph, pw + 1, 5) + AT(ph + 1, pw + 1, 4);
#undef AT
    fmu = S1 / NPIX;
    fvar = (S2 - S1 * S1 / NPIX) / (NPIX - 1.f);
    fg = sqrtf((Gx + Gy) / NGRAD);
  }
#pragma unroll
  for (int off = 32; off > 0; off >>= 1) {
    fmu += __shfl_xor(fmu, off);
    fvar += __shfl_xor(fvar, off);
    fg += __shfl_xor(fg, off);
  }
  const int wave = t >> 6;
  if ((t & 63) == 0) { wsum[wave][0] = fmu; wsum[wave][1] = fvar; wsum[wave][2] = fg; }
  __syncthreads();
  if (t == 0) {
    float m = 0.f, v = 0.f, g = 0.f;
#pragma unroll
    for (int w = 0; w < 8; ++w) { m += wsum[w][0]; v += wsum[w][1]; g += wsum[w][2]; }
    const int b = bc / CHAN, c = bc - b * CHAN;
    featsG[b * 12 + 0 + c] = m / (float)NP;
    featsG[b * 12 + 4 + c] = v / (float)NP;
    featsG[b * 12 + 8 + c] = g / (float)NP;
  }
}

// ---------------------------------------------------------------------------
// Finalize: ONE wave. Register-resident Gauss-Jordan on the augmented 12x24
// system: lane c<24 owns column c (12 f64 registers); pivot row values are
// broadcast with __shfl from lane k. cov is SPD (reference: inv of a
// covariance) so no pivoting is needed for fp32-level accuracy. Then
// Mahalanobis per batch + mean.
// ---------------------------------------------------------------------------
__global__ __launch_bounds__(64) void finalize_kernel(
    const float* __restrict__ featsG, const float* __restrict__ mu0_full,
    const float* __restrict__ cov_full, float* __restrict__ out) {
  __shared__ float feats_s[96];
  __shared__ double inv_s[12][12];
  __shared__ float dist[BATCH];

  const int t = threadIdx.x;   // one wave: 0..63
  feats_s[t] = featsG[t];
  if (t < 32) feats_s[64 + t] = featsG[64 + t];

  double M[12];
#pragma unroll
  for (int r = 0; r < 12; ++r) {
    double v = 0.0;
    if (t < 12) v = (double)cov_full[r * 36 + t];
    else if (t < 24) v = (t - 12 == r) ? 1.0 : 0.0;
    M[r] = v;
  }

#pragma unroll
  for (int k = 0; k < 12; ++k) {
    const double piv = __shfl(M[k], k);
    const double ip = 1.0 / piv;
    M[k] *= ip;
#pragma unroll
    for (int r = 0; r < 12; ++r) {
      if (r == k) continue;
      const double f = __shfl(M[r], k);   // old M[r][k], read before update
      M[r] -= f * M[k];
    }
  }

  if (t >= 12 && t < 24) {
    const int j = t - 12;
#pragma unroll
    for (int r = 0; r < 12; ++r) inv_s[r][j] = M[r];
  }
  __syncthreads();

  if (t < BATCH) {
    double acc = 0.0;
    double d[12];
#pragma unroll
    for (int i = 0; i < 12; ++i)
      d[i] = (double)feats_s[t * 12 + i] - (double)mu0_full[i];
#pragma unroll
    for (int i = 0; i < 12; ++i) {
      double row = 0.0;
#pragma unroll
      for (int j = 0; j < 12; ++j) row += inv_s[i][j] * d[j];
      acc += d[i] * row;
    }
    dist[t] = (float)sqrt(acc);
  }
  __syncthreads();
  if (t == 0) {
    float m = 0.f;
#pragma unroll
    for (int b = 0; b < BATCH; ++b) m += dist[b];
    out[0] = m / (float)BATCH;
  }
}

extern "C" void kernel_launch(void* const* d_in, const int* in_sizes, int n_in,
                              void* d_out, int out_size, void* d_ws, size_t ws_size,
                              hipStream_t stream) {
  const float* x   = (const float*)d_in[0];
  const float* mu0 = (const float*)d_in[1];
  const float* cov = (const float*)d_in[2];
  float* out = (float*)d_out;
  float* pf     = (float*)d_ws;                                   // 32*22*132 floats = 371.7 KB
  float* featsG = pf + (size_t)NBC * NBAND * NCHUNK * NSTAT;      // 96 floats

  band_stats_kernel<<<NBC * NBAND, 576, 0, stream>>>(x, pf);
  patch_feats_kernel<<<NBC, 512, 0, stream>>>(pf, featsG);
  finalize_kernel<<<1, 64, 0, stream>>>(featsG, mu0, cov, out);
}